// Round 2
// baseline (555.476 us; speedup 1.0000x reference)
//
#include <hip/hip_runtime.h>
#include <hip/hip_bf16.h>

// Bilinear resample, zero-padding OOB semantics.
// imgs: (B,H,W,1) f32, dvfs: (B,H,W,2) f32 (ch0 = x offset, ch1 = y offset)
// out:  (B,H,W,1) f32.  B=32, H=W=1024.
//
// R2: 2D tiles (128x8) + XCD-contiguous block swizzle so vertically adjacent
// tiles share imgs halo rows in the same XCD's L2; nontemporal dvfs/out so the
// stream-once data doesn't evict imgs from L2/L3.

#define H_DIM 1024
#define W_DIM 1024
#define TILE_W 128
#define TILE_H 8
#define TY_N (H_DIM / TILE_H)   // 128 tiles vertically
#define TX_N (W_DIM / TILE_W)   // 8 tiles horizontally

typedef float vf4 __attribute__((ext_vector_type(4)));

__device__ __forceinline__ float gather_zp(const float* __restrict__ img,
                                           int yy, int xx) {
    bool valid = (xx >= 0) & (xx < W_DIM) & (yy >= 0) & (yy < H_DIM);
    int xc = min(max(xx, 0), W_DIM - 1);
    int yc = min(max(yy, 0), H_DIM - 1);
    float v = img[yc * W_DIM + xc];
    return valid ? v : 0.0f;
}

__global__ __launch_bounds__(256) void bilerp_kernel(
        const float* __restrict__ imgs,
        const float* __restrict__ dvfs,
        float* __restrict__ out,
        int nblocks) {
    // XCD-contiguous swizzle: hardware round-robins blockIdx over 8 XCDs.
    // Give XCD k the contiguous virtual range [k*chunk, (k+1)*chunk) so each
    // XCD walks whole vertical strips -> halo rows reused in its own L2.
    int j = blockIdx.x;
    int chunk = nblocks >> 3;                 // nblocks divisible by 8
    int v = (j & 7) * chunk + (j >> 3);

    int ty   = v % TY_N;                      // ty fastest: descend a strip
    int rest = v / TY_N;
    int tx   = rest % TX_N;
    int b    = rest / TX_N;

    int t = threadIdx.x;
    int x = tx * TILE_W + (t & 31) * 4;       // 32 threads cover 128 px
    int y = ty * TILE_H + (t >> 5);           // 8 rows per tile

    const float* __restrict__ img = imgs + (size_t)b * (H_DIM * W_DIM);
    size_t pix = ((size_t)b * H_DIM + y) * W_DIM + x;

    // 8 dvfs floats for 4 pixels: two coalesced nontemporal float4 loads
    const vf4* dvf4 = (const vf4*)(dvfs + pix * 2);
    vf4 d0 = __builtin_nontemporal_load(dvf4);
    vf4 d1 = __builtin_nontemporal_load(dvf4 + 1);
    float dx[4] = {d0.x, d0.z, d1.x, d1.z};
    float dy[4] = {d0.y, d0.w, d1.y, d1.w};

    vf4 res;
    #pragma unroll
    for (int i = 0; i < 4; ++i) {
        float fx = (float)(x + i) + dx[i];
        float fy = (float)y       + dy[i];
        float x0f = floorf(fx);
        float y0f = floorf(fy);
        float wx = fx - x0f;
        float wy = fy - y0f;
        int x0 = (int)x0f;
        int y0 = (int)y0f;
        int x1 = x0 + 1;
        int y1 = y0 + 1;

        float v00 = gather_zp(img, y0, x0);
        float v01 = gather_zp(img, y0, x1);
        float v10 = gather_zp(img, y1, x0);
        float v11 = gather_zp(img, y1, x1);

        res[i] = v00 * (1.0f - wx) * (1.0f - wy)
               + v01 * wx          * (1.0f - wy)
               + v10 * (1.0f - wx) * wy
               + v11 * wx          * wy;
    }

    __builtin_nontemporal_store(res, (vf4*)(out + pix));
}

extern "C" void kernel_launch(void* const* d_in, const int* in_sizes, int n_in,
                              void* d_out, int out_size, void* d_ws, size_t ws_size,
                              hipStream_t stream) {
    const float* imgs = (const float*)d_in[0];
    const float* dvfs = (const float*)d_in[1];
    float* out = (float*)d_out;

    int px_per_block = 256 * 4;               // 1024 px per block
    int nblocks = out_size / px_per_block;    // 32768

    bilerp_kernel<<<nblocks, 256, 0, stream>>>(imgs, dvfs, out, nblocks);
}